// Round 5
// baseline (268.250 us; speedup 1.0000x reference)
//
#include <hip/hip_runtime.h>
#include <math.h>

// Problem constants (from reference)
#define N_ROWS 8192
#define B_CH   64
#define L_SEQ  256
#define D_DIM  128
#define KEEP   64
#define HID    1024
#define KTOT   8320            // 128 (q) + 64*128 (packed); log_count handled in epilogue

// bf16 staging buffer layout (elements)
#define KOFF   (N_ROWS * D_DIM)              // 1,048,576  : start of k-chains
#define ZOFF   (KOFF + B_CH * L_SEQ * D_DIM) // 3,145,728  : zero page (128 elems)
#define BUF_ELEMS (ZOFF + 128)               // 3,145,856

// prep task partition (block ranges; pack FIRST so its latency-bound blocks start early)
#define PACK_BLOCKS 256                      // 32 rows each
#define QK_BLOCKS   1537                     // ceil(393232/256)
#define W1T_BLOCKS  2080                     // 130 k-tiles x 16 h-tiles
#define OUT_BLOCKS  32
#define PREP_GRID   (PACK_BLOCKS + QK_BLOCKS + W1T_BLOCKS + OUT_BLOCKS)

typedef unsigned short ushort_t;
typedef __attribute__((ext_vector_type(8))) short  short8;   // 8 bf16 = 4 VGPRs (MFMA A/B frag)
typedef __attribute__((ext_vector_type(4))) float  float4v;  // MFMA C/D frag

// fp32 -> bf16 round-to-nearest-even (inputs finite; no NaN handling needed)
__device__ __forceinline__ ushort_t f2bf(float f) {
    union { float f; unsigned int u; } v; v.f = f;
    unsigned int u = v.u;
    unsigned int r = u + 0x7fffu + ((u >> 16) & 1u);
    return (ushort_t)(r >> 16);
}

// async global->LDS, 16B per lane; LDS dest = wave-uniform base + lane*16.
__device__ __forceinline__ void glds16(const void* g, void* l) {
    __builtin_amdgcn_global_load_lds(
        (const __attribute__((address_space(1))) unsigned int*)g,
        (__attribute__((address_space(3))) unsigned int*)l,
        16, 0, 0);
}

// ---- fused prep: pack | conv_qk | conv_w1t | init_out in ONE dispatch ----
__global__ void prep(const float* __restrict__ q, const float* __restrict__ k,
                     const float* __restrict__ W1, const int* __restrict__ mask,
                     const int* __restrict__ batch_idx, const int* __restrict__ count,
                     const float* __restrict__ b2,
                     ushort_t* __restrict__ buf, ushort_t* __restrict__ w1t,
                     int* __restrict__ srcLUT, float* __restrict__ logc,
                     float* __restrict__ out) {
    __shared__ __align__(16) char smem[16640];   // max(w1t tile 16640, pack 8448)
    const int blk = blockIdx.x;
    const int t = threadIdx.x;

    if (blk < PACK_BLOCKS) {
        // ---- pack: 32 rows/block; ballot-rank; coalesced LUT writes ----
        const int n0 = blk * 32;
        int* sidx = (int*)smem;                    // [32][65] (pad 65 -> conflict-free)
        int* bidx_l = (int*)(smem + 32 * 65 * 4);  // [32]
        for (int i = t; i < 32 * 65; i += 256) sidx[i] = -1;
        if (t < 32) {
            int n = n0 + t;
            bidx_l[t] = batch_idx[n];
            logc[n] = log1pf((float)count[n]);
            srcLUT[n] = n * D_DIM;                 // bi=0: q row offset
        }
        __syncthreads();
        const int w = t >> 6, l = t & 63;
        const unsigned long long ltm = (1ull << l) - 1ull;
        for (int r = 0; r < 8; ++r) {              // wave w: rows w*8 .. w*8+7
            const int lr = w * 8 + r;
            const int* mrow = mask + (size_t)(n0 + lr) * L_SEQ;
            int m0 = mrow[l] != 0;
            int m1 = mrow[64 + l] != 0;
            int m2 = mrow[128 + l] != 0;
            int m3 = mrow[192 + l] != 0;
            unsigned long long b0 = __ballot(m0), b1 = __ballot(m1);
            unsigned long long b2v = __ballot(m2), b3 = __ballot(m3);
            int p1 = (int)__popcll(b0);
            int p2 = p1 + (int)__popcll(b1);
            int p3 = p2 + (int)__popcll(b2v);
            int* row = sidx + lr * 65;
            if (m0) { int rk = (int)__popcll(b0 & ltm);       if (rk < KEEP) row[rk] = l; }
            if (m1) { int rk = p1 + (int)__popcll(b1 & ltm);  if (rk < KEEP) row[rk] = 64 + l; }
            if (m2) { int rk = p2 + (int)__popcll(b2v & ltm); if (rk < KEEP) row[rk] = 128 + l; }
            if (m3) { int rk = p3 + (int)__popcll(b3 & ltm);  if (rk < KEEP) row[rk] = 192 + l; }
        }
        __syncthreads();
        // write phase: per j, 32 consecutive n -> 128-B coalesced segments
        for (int e = t; e < KEEP * 32; e += 256) {
            int j = e >> 5, nl = e & 31;
            int s = sidx[nl * 65 + j];
            srcLUT[(size_t)(j + 1) * N_ROWS + n0 + nl] =
                (s >= 0) ? (KOFF + (bidx_l[nl] * L_SEQ + s) * D_DIM) : ZOFF;
        }

    } else if (blk < PACK_BLOCKS + QK_BLOCKS) {
        // ---- q,k -> bf16 buf + zero page ----
        int c = (blk - PACK_BLOCKS) * 256 + t;
        if (c >= BUF_ELEMS / 8) return;
        int e = c * 8;
        float4 x0, x1;
        if (e < KOFF) {
            const float4* s = (const float4*)(q + e);
            x0 = s[0]; x1 = s[1];
        } else if (e < ZOFF) {
            const float4* s = (const float4*)(k + (e - KOFF));
            x0 = s[0]; x1 = s[1];
        } else {
            x0 = make_float4(0.f, 0.f, 0.f, 0.f);
            x1 = x0;
        }
        union { ushort_t s[8]; uint4 v; } o;
        o.s[0] = f2bf(x0.x); o.s[1] = f2bf(x0.y); o.s[2] = f2bf(x0.z); o.s[3] = f2bf(x0.w);
        o.s[4] = f2bf(x1.x); o.s[5] = f2bf(x1.y); o.s[6] = f2bf(x1.z); o.s[7] = f2bf(x1.w);
        *(uint4*)(buf + e) = o.v;

    } else if (blk < PACK_BLOCKS + QK_BLOCKS + W1T_BLOCKS) {
        // ---- W1 -> bf16 transposed w1t[h][k], 16B coalesced writes ----
        const int idx = blk - (PACK_BLOCKS + QK_BLOCKS);
        const int k0 = (idx % 130) * 64, h0 = (idx / 130) * 64;
        float (*tile)[65] = (float(*)[65])smem;   // +1 pad
        const int hl = t & 63, kl = t >> 6;
#pragma unroll
        for (int i = 0; i < 16; ++i) {
            int kk = kl + i * 4;
            tile[kk][hl] = W1[(size_t)(k0 + kk) * HID + h0 + hl];
        }
        __syncthreads();
#pragma unroll
        for (int i = 0; i < 2; ++i) {
            int chunk = i * 256 + t;
            int h = chunk >> 3, piece = chunk & 7;
            union { ushort_t s[8]; uint4 v; } o;
#pragma unroll
            for (int j = 0; j < 8; ++j) o.s[j] = f2bf(tile[piece * 8 + j][h]);
            *(uint4*)(w1t + (size_t)(h0 + h) * KTOT + k0 + piece * 8) = o.v;
        }

    } else {
        // ---- out[n] = b2 (atomic accumulation base) ----
        int i = (blk - (PACK_BLOCKS + QK_BLOCKS + W1T_BLOCKS)) * 256 + t;
        if (i < N_ROWS) out[i] = b2[0];
    }
}

// ---- gemm: producer/consumer wave-specialized gather-GEMM ----------------
// Block 256 thr = 4 waves: waves 0-1 CONSUMERS (each 64(M)x128(H) tile, 4x8
// MFMA 16x16x32), waves 2-3 PRODUCERS (stage BK=64 chunks via global_load_lds
// into ping-pong LDS + own the srcLUT gather-offset prefetch).
// Key: consumers issue ZERO global loads in the loop, so their s_barrier entry
// has no vmcnt drain; producers' vmcnt(0) drain overlaps consumer compute.
// LDS: 2 x (16+16) KB = 64 KB -> 2 blocks/CU (8 waves/CU).
__global__ __launch_bounds__(256, 2)
void gemm_mlp(const ushort_t* __restrict__ buf, const ushort_t* __restrict__ w1t,
              const int* __restrict__ srcLUT, const float* __restrict__ logc,
              const float* __restrict__ W1, const float* __restrict__ b1,
              const float* __restrict__ W2, float* __restrict__ out) {
    __shared__ ushort_t As[2][128 * 64];   // [row][k] with 16B-slot XOR swizzle
    __shared__ ushort_t Bs[2][128 * 64];

    const int t = threadIdx.x;
    const int blkH = blockIdx.x, blkM = blockIdx.y;   // x=8 -> XCD-pinned B slice
    const int wave = t >> 6, lane = t & 63;
    const int ln = lane & 15, quad = lane >> 4;

    if (wave >= 2) {
        // ================= PRODUCER =================
        const int u = (wave - 2) * 64 + lane;       // 0..127
        const int tr8 = u >> 3;                     // 0..15 (row sub-index)
        const int pg = (u & 7) ^ (tr8 & 7);         // swizzled global 16B piece
        const ushort_t* gBp[8];
#pragma unroll
        for (int i = 0; i < 8; ++i)
            gBp[i] = w1t + (size_t)(blkH * 128 + i * 16 + tr8) * KTOT + pg * 8;
        const int* lut = srcLUT + blkM * 128 + tr8;

        int offC[8], offP[8];
#pragma unroll
        for (int i = 0; i < 8; ++i) offC[i] = lut[i * 16];           // bi=0 (q rows)
        // prestage chunk 0 (bi=0, half=0) into buffer 0
#pragma unroll
        for (int i = 0; i < 8; ++i) {
            glds16(buf + offC[i] + pg * 8, &As[0][i * 1024 + u * 8]);
            glds16(gBp[i], &Bs[0][i * 1024 + u * 8]);
        }
#pragma unroll
        for (int i = 0; i < 8; ++i) offP[i] = lut[N_ROWS + i * 16];  // bi=1
        __syncthreads();                      // chunk 0 published

        int p = 0;
        for (int ch = 0; ch < 130; ++ch) {
            const int nx = ch + 1;
            if (nx < 130) {
                const int half = nx & 1;
                if (half == 0) {
#pragma unroll
                    for (int i = 0; i < 8; ++i) offC[i] = offP[i];   // next bi begins
                }
                ushort_t* dA = &As[p ^ 1][0];
                ushort_t* dB = &Bs[p ^ 1][0];
#pragma unroll
                for (int i = 0; i < 8; ++i) {
                    glds16(buf + offC[i] + half * 64 + pg * 8, dA + i * 1024 + u * 8);
                    glds16(gBp[i] + nx * 64, dB + i * 1024 + u * 8);
                }
                if (half == 0) {
                    const int nb = (nx >> 1) + 1;                    // prefetch bi=nb
                    if (nb < 65) {
#pragma unroll
                        for (int i = 0; i < 8; ++i) offP[i] = lut[nb * N_ROWS + i * 16];
                    }
                }
            }
            __syncthreads();                  // producer drain overlaps consumer compute
            p ^= 1;
        }
        // producers done — no epilogue
    } else {
        // ================= CONSUMER =================
        const int wm = wave;                  // 0..1 : M-half of the 128x128 tile
        float4v acc[4][8];
#pragma unroll
        for (int i = 0; i < 4; ++i)
#pragma unroll
            for (int j = 0; j < 8; ++j)
#pragma unroll
                for (int r = 0; r < 4; ++r) acc[i][j][r] = 0.0f;

        __syncthreads();                      // matches producer prestage barrier
        int p = 0;
        for (int ch = 0; ch < 130; ++ch) {
            const ushort_t* rA = &As[p][0];
            const ushort_t* rB = &Bs[p][0];
#pragma unroll
            for (int kk = 0; kk < 2; ++kk) {
                const int sl = (kk * 4 + quad) ^ (ln & 7);
                short8 af[4], bq[8];
#pragma unroll
                for (int mi = 0; mi < 4; ++mi) {
                    const int row = wm * 64 + mi * 16 + ln;   // row&7 == ln&7
                    af[mi] = *(const short8*)(rA + row * 64 + sl * 8);
                }
#pragma unroll
                for (int ni = 0; ni < 8; ++ni) {
                    const int row = ni * 16 + ln;
                    bq[ni] = *(const short8*)(rB + row * 64 + sl * 8);
                }
#pragma unroll
                for (int mi = 0; mi < 4; ++mi)
#pragma unroll
                    for (int ni = 0; ni < 8; ++ni)
                        acc[mi][ni] = __builtin_amdgcn_mfma_f32_16x16x32_bf16(
                            af[mi], bq[ni], acc[mi][ni], 0, 0, 0);
            }
            __syncthreads();
            p ^= 1;
        }

        // Epilogue: pre = acc + logc[n]*W1[last,h] + b1[h]; gelu(exact); dot W2.
        // C/D layout (verified m89/m91): col = lane&15, row = quad*4 + reg.
        const float* w1last = W1 + (size_t)KTOT * HID;
        float w1l[8], b1v[8], w2v[8];
#pragma unroll
        for (int ni = 0; ni < 8; ++ni) {
            int h = blkH * 128 + ni * 16 + ln;
            w1l[ni] = w1last[h];
            b1v[ni] = b1[h];
            w2v[ni] = W2[h];
        }
        const int nbase = blkM * 128 + wm * 64 + quad * 4;
#pragma unroll
        for (int mi = 0; mi < 4; ++mi) {
#pragma unroll
            for (int rg = 0; rg < 4; ++rg) {
                const int n = nbase + mi * 16 + rg;
                const float lc = logc[n];
                float s = 0.0f;
#pragma unroll
                for (int ni = 0; ni < 8; ++ni) {
                    float pre = acc[mi][ni][rg] + lc * w1l[ni] + b1v[ni];
                    float hv = 0.5f * pre * (1.0f + erff(pre * 0.70710678118654752f));
                    s += hv * w2v[ni];
                }
                s += __shfl_xor(s, 1);
                s += __shfl_xor(s, 2);
                s += __shfl_xor(s, 4);
                s += __shfl_xor(s, 8);
                if (ln == 0) atomicAdd(out + n, s);
            }
        }
    }
}

// ---- launch --------------------------------------------------------------
extern "C" void kernel_launch(void* const* d_in, const int* in_sizes, int n_in,
                              void* d_out, int out_size, void* d_ws, size_t ws_size,
                              hipStream_t stream) {
    const float* q     = (const float*)d_in[0];
    const float* k     = (const float*)d_in[1];
    const int*   bidx  = (const int*)d_in[2];
    const int*   mask  = (const int*)d_in[3];
    const int*   count = (const int*)d_in[4];
    const float* W1    = (const float*)d_in[5];
    const float* b1    = (const float*)d_in[6];
    const float* W2    = (const float*)d_in[7];
    const float* b2    = (const float*)d_in[8];
    float* out = (float*)d_out;

    // workspace layout (bytes): buf 6,291,712 | w1t 17,039,360 | srcLUT 2,129,920 | logc 32,768
    char* ws = (char*)d_ws;
    ushort_t* buf    = (ushort_t*)(ws);
    ushort_t* w1t    = (ushort_t*)(ws + 6291712);
    int*      srcLUT = (int*)(ws + 6291712 + 17039360);
    float*    logc   = (float*)(ws + 6291712 + 17039360 + 2129920);

    prep<<<PREP_GRID, 256, 0, stream>>>(q, k, W1, mask, bidx, count, b2,
                                        buf, w1t, srcLUT, logc, out);
    gemm_mlp<<<dim3(HID / 128, N_ROWS / 128), 256, 0, stream>>>(
        buf, w1t, srcLUT, logc, W1, b1, W2, out);
}

// Round 6
// 242.980 us; speedup vs baseline: 1.1040x; 1.1040x over previous
//
#include <hip/hip_runtime.h>
#include <math.h>

// Problem constants (from reference)
#define N_ROWS 8192
#define B_CH   64
#define L_SEQ  256
#define D_DIM  128
#define KEEP   64
#define HID    1024
#define KTOT   8320            // 128 (q) + 64*128 (packed); log_count handled in epilogue
#define KTILES 260             // KTOT/32
#define HTILES 64              // HID/16

// bf16 staging buffer layout (elements)
#define KOFF   (N_ROWS * D_DIM)              // 1,048,576  : start of k-chains
#define ZOFF   (KOFF + B_CH * L_SEQ * D_DIM) // 3,145,728  : zero page (128 elems)
#define BUF_ELEMS (ZOFF + 128)               // 3,145,856

// prep task partition (pack FIRST: latency-bound blocks start early; out-init folded in)
#define PACK_BLOCKS 256                      // 32 rows each (+ out[n]=b2)
#define QK_BLOCKS   1537                     // ceil(393232/256)
#define W1T_BLOCKS  2080                     // 130 k64-tiles x 16 h64-tiles
#define PREP_GRID   (PACK_BLOCKS + QK_BLOCKS + W1T_BLOCKS)

typedef unsigned short ushort_t;
typedef __attribute__((ext_vector_type(8))) short  short8;   // 8 bf16 = 4 VGPRs (MFMA A/B frag)
typedef __attribute__((ext_vector_type(4))) float  float4v;  // MFMA C/D frag

// fp32 -> bf16 round-to-nearest-even (inputs finite; no NaN handling needed)
__device__ __forceinline__ ushort_t f2bf(float f) {
    union { float f; unsigned int u; } v; v.f = f;
    unsigned int u = v.u;
    unsigned int r = u + 0x7fffu + ((u >> 16) & 1u);
    return (ushort_t)(r >> 16);
}

// async global->LDS, 16B per lane; LDS dest = wave-uniform base + lane*16.
__device__ __forceinline__ void glds16(const void* g, void* l) {
    __builtin_amdgcn_global_load_lds(
        (const __attribute__((address_space(1))) unsigned int*)g,
        (__attribute__((address_space(3))) unsigned int*)l,
        16, 0, 0);
}

// ---- fused prep: pack(+out) | conv_qk | conv_w1frag in ONE dispatch ------
// w1frag layout: for (h,k): hT=h>>4, ln=h&15, kT=k>>5, quad=(k>>3)&3, j=k&7
//   elem addr = ((hT*KTILES + kT)*64 + (quad*16+ln))*8 + j
// so a gemm wave's B-frag load (lane l = quad*16+ln) is base + l*16B: 1KB contiguous.
__global__ void prep(const float* __restrict__ q, const float* __restrict__ k,
                     const float* __restrict__ W1, const int* __restrict__ mask,
                     const int* __restrict__ batch_idx, const int* __restrict__ count,
                     const float* __restrict__ b2,
                     ushort_t* __restrict__ buf, ushort_t* __restrict__ w1f,
                     int* __restrict__ srcLUT, float* __restrict__ logc,
                     float* __restrict__ out) {
    __shared__ __align__(16) char smem[16640];   // max(w1t tile 16640, pack 8448)
    const int blk = blockIdx.x;
    const int t = threadIdx.x;

    if (blk < PACK_BLOCKS) {
        // ---- pack: 32 rows/block; ballot-rank; coalesced LUT writes; out init ----
        const int n0 = blk * 32;
        int* sidx = (int*)smem;                    // [32][65] (pad 65 -> conflict-free)
        int* bidx_l = (int*)(smem + 32 * 65 * 4);  // [32]
        for (int i = t; i < 32 * 65; i += 256) sidx[i] = -1;
        if (t < 32) {
            int n = n0 + t;
            bidx_l[t] = batch_idx[n];
            logc[n] = log1pf((float)count[n]);
            srcLUT[n] = n * D_DIM;                 // bi=0: q row offset
            out[n] = b2[0];                        // atomic accumulation base
        }
        __syncthreads();
        const int w = t >> 6, l = t & 63;
        const unsigned long long ltm = (1ull << l) - 1ull;
        for (int r = 0; r < 8; ++r) {              // wave w: rows w*8 .. w*8+7
            const int lr = w * 8 + r;
            const int* mrow = mask + (size_t)(n0 + lr) * L_SEQ;
            int m0 = mrow[l] != 0;
            int m1 = mrow[64 + l] != 0;
            int m2 = mrow[128 + l] != 0;
            int m3 = mrow[192 + l] != 0;
            unsigned long long b0 = __ballot(m0), b1 = __ballot(m1);
            unsigned long long b2v = __ballot(m2), b3 = __ballot(m3);
            int p1 = (int)__popcll(b0);
            int p2 = p1 + (int)__popcll(b1);
            int p3 = p2 + (int)__popcll(b2v);
            int* row = sidx + lr * 65;
            if (m0) { int rk = (int)__popcll(b0 & ltm);       if (rk < KEEP) row[rk] = l; }
            if (m1) { int rk = p1 + (int)__popcll(b1 & ltm);  if (rk < KEEP) row[rk] = 64 + l; }
            if (m2) { int rk = p2 + (int)__popcll(b2v & ltm); if (rk < KEEP) row[rk] = 128 + l; }
            if (m3) { int rk = p3 + (int)__popcll(b3 & ltm);  if (rk < KEEP) row[rk] = 192 + l; }
        }
        __syncthreads();
        // write phase: per j, 32 consecutive n -> 128-B coalesced segments
        for (int e = t; e < KEEP * 32; e += 256) {
            int j = e >> 5, nl = e & 31;
            int s = sidx[nl * 65 + j];
            srcLUT[(size_t)(j + 1) * N_ROWS + n0 + nl] =
                (s >= 0) ? (KOFF + (bidx_l[nl] * L_SEQ + s) * D_DIM) : ZOFF;
        }

    } else if (blk < PACK_BLOCKS + QK_BLOCKS) {
        // ---- q,k -> bf16 buf + zero page ----
        int c = (blk - PACK_BLOCKS) * 256 + t;
        if (c >= BUF_ELEMS / 8) return;
        int e = c * 8;
        float4 x0, x1;
        if (e < KOFF) {
            const float4* s = (const float4*)(q + e);
            x0 = s[0]; x1 = s[1];
        } else if (e < ZOFF) {
            const float4* s = (const float4*)(k + (e - KOFF));
            x0 = s[0]; x1 = s[1];
        } else {
            x0 = make_float4(0.f, 0.f, 0.f, 0.f);
            x1 = x0;
        }
        union { ushort_t s[8]; uint4 v; } o;
        o.s[0] = f2bf(x0.x); o.s[1] = f2bf(x0.y); o.s[2] = f2bf(x0.z); o.s[3] = f2bf(x0.w);
        o.s[4] = f2bf(x1.x); o.s[5] = f2bf(x1.y); o.s[6] = f2bf(x1.z); o.s[7] = f2bf(x1.w);
        *(uint4*)(buf + e) = o.v;

    } else {
        // ---- W1 -> bf16 in MFMA-fragment order (LDS-transposed 64x64 tile) ----
        const int idx = blk - (PACK_BLOCKS + QK_BLOCKS);
        const int k0 = (idx % 130) * 64, h0 = (idx / 130) * 64;
        float (*tile)[65] = (float(*)[65])smem;   // +1 pad
        const int hl = t & 63, kl = t >> 6;
#pragma unroll
        for (int i = 0; i < 16; ++i) {
            int kk = kl + i * 4;
            tile[kk][hl] = W1[(size_t)(k0 + kk) * HID + h0 + hl];
        }
        __syncthreads();
        // 8 chunks of 1KB: chunk c = qt*4 + ht (qt: k-32-tile 0..1, ht: h-16-tile 0..3)
        // slot s = i*256 + t: c = s>>6, lane l = s&63 (ln=l&15, quad=l>>4)
#pragma unroll
        for (int i = 0; i < 2; ++i) {
            int s = i * 256 + t;
            int c = s >> 6, l = s & 63;
            int qt = c >> 2, ht = c & 3;
            int ln = l & 15, quad = l >> 4;
            union { ushort_t sv[8]; uint4 v; } o;
#pragma unroll
            for (int j = 0; j < 8; ++j)
                o.sv[j] = f2bf(tile[qt * 32 + quad * 8 + j][ht * 16 + ln]);
            size_t dst = (((size_t)(h0 / 16 + ht) * KTILES + (k0 / 32 + qt)) * 64 + l) * 8;
            *(uint4*)(w1f + dst) = o.v;
        }
    }
}

// ---- gemm: gather-GEMM + gelu + @W2; A via LDS, B DIRECT from L2 ---------
// C-tile 128(n) x 128(h), BK=128, 4 waves 2x2, wave = 4x4 MFMA 16x16x32/k-step.
// B-frags load as 1KB lane-contiguous global reads from the fragment-ordered
// w1f (XCD-pinned 2.1MB slice, L2-resident via blkH=blockIdx.x swizzle) -> no
// Bs LDS tile: per-CU LDS traffic halves (384->192 KB/bi), the R3 binder.
__global__ __launch_bounds__(256, 2)
void gemm_mlp(const ushort_t* __restrict__ buf, const ushort_t* __restrict__ w1f,
              const int* __restrict__ srcLUT, const float* __restrict__ logc,
              const float* __restrict__ W1, const float* __restrict__ b1,
              const float* __restrict__ W2, float* __restrict__ out) {
    __shared__ ushort_t As[128 * 128];   // 32 KB, [row][k] with 16B-slot XOR swizzle

    const int t = threadIdx.x;
    const int blkH = blockIdx.x, blkM = blockIdx.y;   // x=8 -> XCD-pinned B slice
    const int wave = t >> 6, lane = t & 63;
    const int wm = wave >> 1, wh = wave & 1;
    const int ln = lane & 15, quad = lane >> 4;

    float4v acc[4][4];
#pragma unroll
    for (int i = 0; i < 4; ++i)
#pragma unroll
        for (int j = 0; j < 4; ++j)
#pragma unroll
            for (int r = 0; r < 4; ++r) acc[i][j][r] = 0.0f;

    // A staging: pass i (0..7), chunk c=i*256+t; row=i*16+(t>>4); LDS slot=t&15;
    // global piece pg = slot ^ (row&15) = (t&15)^(t>>4)  (pass-invariant).
    const int tr = t >> 4;
    const int pg = (t & 15) ^ tr;
    ushort_t* lA = As + t * 8;
    const int* lutBase = srcLUT + blkM * 128 + tr;

    // B fragment pointers: per ni, chunk base for (hT = blkH*8 + wh*4 + ni),
    // lane-contiguous: + lane*8 elems; per (bi,kk): + (bi*4+kk)*512 elems.
    const ushort_t* bp[4];
#pragma unroll
    for (int ni = 0; ni < 4; ++ni)
        bp[ni] = w1f + ((size_t)(blkH * 8 + wh * 4 + ni) * KTILES * 64 + lane) * 8;

    int offA[8];
#pragma unroll
    for (int i = 0; i < 8; ++i) offA[i] = lutBase[i * 16];   // bi = 0 (q rows)

    for (int bi = 0; bi < 65; ++bi) {
        // stage A(bi) into LDS
#pragma unroll
        for (int i = 0; i < 8; ++i)
            glds16(buf + offA[i] + pg * 8, lA + i * 2048);
        // load all B(bi) fragments into registers (drained by the same barrier)
        short8 bq[4][4];
#pragma unroll
        for (int kk = 0; kk < 4; ++kk)
#pragma unroll
            for (int ni = 0; ni < 4; ++ni)
                bq[kk][ni] = *(const short8*)(bp[ni] + (size_t)(bi * 4 + kk) * 512);
        // prefetch next bi's gather offsets
        int offN[8];
        if (bi < 64) {
#pragma unroll
            for (int i = 0; i < 8; ++i) offN[i] = lutBase[(bi + 1) * N_ROWS + i * 16];
        }
        __syncthreads();                      // drains vmcnt (glds + B loads)
#pragma unroll
        for (int kk = 0; kk < 4; ++kk) {
            short8 af[4];
#pragma unroll
            for (int mi = 0; mi < 4; ++mi) {
                const int row = wm * 64 + mi * 16 + ln;          // row&15 == ln
                const int sl = (kk * 4 + quad) ^ ln;
                af[mi] = *(const short8*)(As + row * 128 + sl * 8);
            }
#pragma unroll
            for (int mi = 0; mi < 4; ++mi)
#pragma unroll
                for (int ni = 0; ni < 4; ++ni)
                    acc[mi][ni] = __builtin_amdgcn_mfma_f32_16x16x32_bf16(
                        af[mi], bq[kk][ni], acc[mi][ni], 0, 0, 0);
        }
        __syncthreads();                      // As reads done before next overwrite
#pragma unroll
        for (int i = 0; i < 8; ++i) offA[i] = offN[i];
    }

    // Epilogue: pre = acc + logc[n]*W1[last,h] + b1[h]; gelu(exact); dot W2; atomic out.
    // C/D layout (verified m89/m91): col = lane&15 (h), row = quad*4 + reg (n).
    const float* w1last = W1 + (size_t)KTOT * HID;
    float w1l[4], b1v[4], w2v[4];
#pragma unroll
    for (int ni = 0; ni < 4; ++ni) {
        int h = blkH * 128 + wh * 64 + ni * 16 + ln;
        w1l[ni] = w1last[h];
        b1v[ni] = b1[h];
        w2v[ni] = W2[h];
    }
    const int nbase = blkM * 128 + wm * 64 + quad * 4;
#pragma unroll
    for (int mi = 0; mi < 4; ++mi) {
#pragma unroll
        for (int rg = 0; rg < 4; ++rg) {
            const int n = nbase + mi * 16 + rg;
            const float lc = logc[n];
            float s = 0.0f;
#pragma unroll
            for (int ni = 0; ni < 4; ++ni) {
                float pre = acc[mi][ni][rg] + lc * w1l[ni] + b1v[ni];
                float hv = 0.5f * pre * (1.0f + erff(pre * 0.70710678118654752f));
                s += hv * w2v[ni];
            }
            s += __shfl_xor(s, 1);
            s += __shfl_xor(s, 2);
            s += __shfl_xor(s, 4);
            s += __shfl_xor(s, 8);
            if (ln == 0) atomicAdd(out + n, s);
        }
    }
}

// ---- launch --------------------------------------------------------------
extern "C" void kernel_launch(void* const* d_in, const int* in_sizes, int n_in,
                              void* d_out, int out_size, void* d_ws, size_t ws_size,
                              hipStream_t stream) {
    const float* q     = (const float*)d_in[0];
    const float* k     = (const float*)d_in[1];
    const int*   bidx  = (const int*)d_in[2];
    const int*   mask  = (const int*)d_in[3];
    const int*   count = (const int*)d_in[4];
    const float* W1    = (const float*)d_in[5];
    const float* b1    = (const float*)d_in[6];
    const float* W2    = (const float*)d_in[7];
    const float* b2    = (const float*)d_in[8];
    float* out = (float*)d_out;

    // workspace layout (bytes): buf 6,291,712 | w1f 17,039,360 | srcLUT 2,129,920 | logc 32,768
    char* ws = (char*)d_ws;
    ushort_t* buf    = (ushort_t*)(ws);
    ushort_t* w1f    = (ushort_t*)(ws + 6291712);
    int*      srcLUT = (int*)(ws + 6291712 + 17039360);
    float*    logc   = (float*)(ws + 6291712 + 17039360 + 2129920);

    prep<<<PREP_GRID, 256, 0, stream>>>(q, k, W1, mask, bidx, count, b2,
                                        buf, w1f, srcLUT, logc, out);
    gemm_mlp<<<dim3(HID / 128, N_ROWS / 128), 256, 0, stream>>>(
        buf, w1f, srcLUT, logc, W1, b1, W2, out);
}